// Round 7
// baseline (719.875 us; speedup 1.0000x reference)
//
#include <hip/hip_runtime.h>
#include <hip/hip_fp8.h>
#include <math.h>

#define NN 100000
#define NE 3200000
#define FIN 128
#define HD 256
#define CO 47
#define COP 64     // padded row for layer-2 gather (one 128B line)
#define NBKT 196   // buckets of 512 nodes: dst>>9
#define G 1024     // partition blocks
#define CHUNK 3125 // NE / G exactly

typedef _Float16 h2 __attribute__((ext_vector_type(2)));
typedef _Float16 h4 __attribute__((ext_vector_type(4)));
typedef _Float16 h8 __attribute__((ext_vector_type(8)));
typedef float f32x4 __attribute__((ext_vector_type(4)));

// ---------------- CSR build via bucketed counting sort ----------------

__global__ __launch_bounds__(256) void hist_kernel(const int* __restrict__ dst,
                                                   int* __restrict__ hist) {
    __shared__ int h[NBKT];
    int tid = threadIdx.x;
    for (int i = tid; i < NBKT; i += 256) h[i] = 0;
    __syncthreads();
    int base = blockIdx.x * CHUNK;
    for (int i = tid; i < CHUNK; i += 256)
        atomicAdd(&h[dst[base + i] >> 9], 1);
    __syncthreads();
    for (int i = tid; i < NBKT; i += 256) hist[i * G + blockIdx.x] = h[i];
}

__global__ void scan1_kernel(const int* __restrict__ in, int* __restrict__ out,
                             int* __restrict__ bsum, int n) {
    __shared__ int tmp[256];
    int t = threadIdx.x;
    int i = blockIdx.x * 256 + t;
    int v = (i < n) ? in[i] : 0;
    tmp[t] = v;
    __syncthreads();
    #pragma unroll
    for (int off = 1; off < 256; off <<= 1) {
        int u = (t >= off) ? tmp[t - off] : 0;
        __syncthreads();
        tmp[t] += u;
        __syncthreads();
    }
    if (i < n) out[i] = tmp[t] - v;
    if (t == 255) bsum[blockIdx.x] = tmp[255];
}

__global__ void scan2_kernel(int* __restrict__ bsum, int nb) {
    __shared__ int tmp[1024];
    int t = threadIdx.x;
    int v = (t < nb) ? bsum[t] : 0;
    tmp[t] = v;
    __syncthreads();
    #pragma unroll
    for (int off = 1; off < 1024; off <<= 1) {
        int u = (t >= off) ? tmp[t - off] : 0;
        __syncthreads();
        tmp[t] += u;
        __syncthreads();
    }
    if (t < nb) bsum[t] = tmp[t] - v;
    if (t == nb - 1) bsum[nb] = tmp[t];
}

__global__ void scan3_kernel(int* __restrict__ out, const int* __restrict__ bsum,
                             int nb, int n) {
    int i = blockIdx.x * 256 + threadIdx.x;
    if (i < n) out[i] += bsum[i >> 8];
    if (i == 0) out[n] = bsum[nb];
}

__global__ __launch_bounds__(256) void scatter_kernel(const int* __restrict__ src,
                                                      const int* __restrict__ dst,
                                                      const int* __restrict__ hscan,
                                                      int* __restrict__ epk) {
    __shared__ int cur[NBKT];
    int tid = threadIdx.x;
    for (int i = tid; i < NBKT; i += 256) cur[i] = hscan[i * G + blockIdx.x];
    __syncthreads();
    int base = blockIdx.x * CHUNK;
    for (int i = tid; i < CHUNK; i += 256) {
        int e = base + i;
        int d = dst[e];
        int slot = atomicAdd(&cur[d >> 9], 1);
        epk[slot] = ((d & 511) << 17) | src[e];
    }
}

__global__ __launch_bounds__(256) void bucket_fill_kernel(
    const int* __restrict__ hscan, const int* __restrict__ epk,
    int* __restrict__ csr, int* __restrict__ offs, float* __restrict__ dinv)
{
    __shared__ int deg[512], cur[512], a0[512], a1[512];
    int tid = threadIdx.x, b = blockIdx.x;
    int ebeg = hscan[b * G], eend = hscan[(b + 1) * G];
    deg[tid] = 0; deg[tid + 256] = 0;
    __syncthreads();
    for (int e = ebeg + tid; e < eend; e += 256)
        atomicAdd(&deg[((unsigned)epk[e]) >> 17], 1);
    __syncthreads();
    a0[tid] = deg[tid]; a0[tid + 256] = deg[tid + 256];
    __syncthreads();
    int* pin = a0; int* pout = a1;
    for (int off = 1; off < 512; off <<= 1) {
        #pragma unroll
        for (int q = 0; q < 2; ++q) {
            int p = tid + q * 256;
            pout[p] = pin[p] + ((p >= off) ? pin[p - off] : 0);
        }
        __syncthreads();
        int* t = pin; pin = pout; pout = t;
    }
    #pragma unroll
    for (int q = 0; q < 2; ++q) {
        int i = tid + q * 256;
        int excl = pin[i] - deg[i];
        cur[i] = excl;
        int node = b * 512 + i;
        if (node < NN) {
            offs[node] = ebeg + excl;
            dinv[node] = rsqrtf((float)deg[i] + 1.0f);
        }
    }
    if (b == 0 && tid == 0) offs[NN] = NE;
    __syncthreads();
    for (int e = ebeg + tid; e < eend; e += 256) {
        int pk = epk[e];
        int p = atomicAdd(&cur[((unsigned)pk) >> 17], 1);
        csr[ebeg + p] = pk & 0x1FFFF;
    }
}

// ---------------- weight convert ----------------

template<int K>
__global__ void wtrans_kernel(const float* __restrict__ W, _Float16* __restrict__ Wt,
                              int N, int NP) {
    int i = blockIdx.x * 256 + threadIdx.x;
    if (i >= NP * K) return;
    int n = i / K, k = i % K;
    float v = (n < N) ? W[(size_t)k * N + n] : 0.0f;
    Wt[i] = (_Float16)v;
}

// ---------------- x -> fp8 e4m3 (OCP), pre-scaled by dinv ----------------

__global__ void conv_x_kernel(const float* __restrict__ x, const float* __restrict__ dinv,
                              unsigned* __restrict__ xq) {
    int i = blockIdx.x * 256 + threadIdx.x;     // over NN*FIN/4
    if (i >= NN * FIN / 4) return;
    int r = i >> 5;
    float4 v = ((const float4*)x)[i];
    float dv = dinv[r];
    __hip_fp8_e4m3 q0(v.x * dv), q1(v.y * dv), q2(v.z * dv), q3(v.w * dv);
    unsigned u = (unsigned)q0.__x | ((unsigned)q1.__x << 8) |
                 ((unsigned)q2.__x << 16) | ((unsigned)q3.__x << 24);
    xq[i] = u;
}

// decode OCP e4m3fn -> float (exact, incl. subnormals): fp16(bits=(u&0x7f)<<7) * 256
__device__ inline float dec8(unsigned u) {
    unsigned short hb = (unsigned short)((u & 0x7Fu) << 7);
    float f = (float)__builtin_bit_cast(_Float16, hb) * 256.0f;
    unsigned fb = __builtin_bit_cast(unsigned, f) ^ ((u & 0x80u) << 24);
    return __builtin_bit_cast(float, fb);
}

// ---------------- aggregation (wave per node, atomic-free) ----------------

__global__ __launch_bounds__(256) void agg128_kernel(
    const unsigned short* __restrict__ xq, const int* __restrict__ offs,
    const int* __restrict__ csr, const float* __restrict__ dinv,
    _Float16* __restrict__ out)
{
    int lane = threadIdx.x & 63;
    int v = blockIdx.x * 4 + (threadIdx.x >> 6);
    unsigned sv = xq[(size_t)v * 64 + lane];    // 2 fp8 per lane
    float ax = dec8(sv & 0xFF), ay = dec8(sv >> 8);
    int b = offs[v], e = offs[v + 1], j = b;
    int s[8];
    if (j + 8 <= e) {
        #pragma unroll
        for (int q = 0; q < 8; ++q) s[q] = csr[j + q];
    }
    for (; j + 8 <= e; ) {
        int nj = j + 8;
        int ns[8];
        if (nj + 8 <= e) {
            #pragma unroll
            for (int q = 0; q < 8; ++q) ns[q] = csr[nj + q];
        }
        #pragma unroll
        for (int q = 0; q < 8; ++q) {
            unsigned t = xq[(size_t)s[q] * 64 + lane];
            ax += dec8(t & 0xFF); ay += dec8(t >> 8);
        }
        #pragma unroll
        for (int q = 0; q < 8; ++q) s[q] = ns[q];
        j = nj;
    }
    for (; j < e; ++j) {
        unsigned t = xq[(size_t)csr[j] * 64 + lane];
        ax += dec8(t & 0xFF); ay += dec8(t >> 8);
    }
    float dv = dinv[v];
    h2 o; o[0] = (_Float16)(ax * dv); o[1] = (_Float16)(ay * dv);
    ((h2*)out)[(size_t)v * 64 + lane] = o;
}

__global__ __launch_bounds__(256) void agg256_kernel(
    const _Float16* __restrict__ hp, const int* __restrict__ offs,
    const int* __restrict__ csr, const float* __restrict__ dinv,
    _Float16* __restrict__ out)
{
    int lane = threadIdx.x & 63;
    int v = blockIdx.x * 4 + (threadIdx.x >> 6);
    const h4* rows = (const h4*)hp;
    h4 sv = rows[(size_t)v * 64 + lane];
    float a0 = (float)sv[0], a1 = (float)sv[1], a2 = (float)sv[2], a3 = (float)sv[3];
    int b = offs[v], e = offs[v + 1], j = b;
    int s[8];
    if (j + 8 <= e) {
        #pragma unroll
        for (int q = 0; q < 8; ++q) s[q] = csr[j + q];
    }
    for (; j + 8 <= e; ) {
        int nj = j + 8;
        int ns[8];
        if (nj + 8 <= e) {
            #pragma unroll
            for (int q = 0; q < 8; ++q) ns[q] = csr[nj + q];
        }
        #pragma unroll
        for (int q = 0; q < 8; ++q) {
            h4 t = rows[(size_t)s[q] * 64 + lane];
            a0 += (float)t[0]; a1 += (float)t[1]; a2 += (float)t[2]; a3 += (float)t[3];
        }
        #pragma unroll
        for (int q = 0; q < 8; ++q) s[q] = ns[q];
        j = nj;
    }
    for (; j < e; ++j) {
        h4 t = rows[(size_t)csr[j] * 64 + lane];
        a0 += (float)t[0]; a1 += (float)t[1]; a2 += (float)t[2]; a3 += (float)t[3];
    }
    float dv = dinv[v];
    h4 o; o[0] = (_Float16)(a0 * dv); o[1] = (_Float16)(a1 * dv);
    o[2] = (_Float16)(a2 * dv); o[3] = (_Float16)(a3 * dv);
    ((h4*)out)[(size_t)v * 64 + lane] = o;
}

__global__ __launch_bounds__(256) void agg47_lsm_kernel(
    const _Float16* __restrict__ t2, const int* __restrict__ offs,
    const int* __restrict__ csr, const float* __restrict__ dinv,
    const float* __restrict__ bias, float* __restrict__ out)
{
    int lane = threadIdx.x & 63;
    int v = blockIdx.x * 4 + (threadIdx.x >> 6);
    float acc = (float)t2[(size_t)v * COP + lane];
    int b = offs[v], e = offs[v + 1], j = b;
    int s[8];
    if (j + 8 <= e) {
        #pragma unroll
        for (int q = 0; q < 8; ++q) s[q] = csr[j + q];
    }
    for (; j + 8 <= e; ) {
        int nj = j + 8;
        int ns[8];
        if (nj + 8 <= e) {
            #pragma unroll
            for (int q = 0; q < 8; ++q) ns[q] = csr[nj + q];
        }
        #pragma unroll
        for (int q = 0; q < 8; ++q) acc += (float)t2[(size_t)s[q] * COP + lane];
        #pragma unroll
        for (int q = 0; q < 8; ++q) s[q] = ns[q];
        j = nj;
    }
    for (; j < e; ++j) acc += (float)t2[(size_t)csr[j] * COP + lane];
    bool act = lane < CO;
    float val = act ? fmaf(acc, dinv[v], bias[lane]) : -1e30f;
    float m = val;
    #pragma unroll
    for (int o = 32; o > 0; o >>= 1) m = fmaxf(m, __shfl_xor(m, o, 64));
    float ex = act ? expf(val - m) : 0.0f;
    float sum = ex;
    #pragma unroll
    for (int o = 32; o > 0; o >>= 1) sum += __shfl_xor(sum, o, 64);
    if (act) out[(size_t)v * CO + lane] = val - m - logf(sum);
}

// ---------------- big MFMA GEMM: BM=128, BN=128, BK=64, 4 waves (2x2), 64x64/wave ----

#define LDS_PAD 8

template<int K, bool XFORM, bool EPI_DINV>
__global__ __launch_bounds__(256) void mfma_gemm_big(
    const _Float16* __restrict__ A, int lda,
    const _Float16* __restrict__ Wt,
    const float* __restrict__ ss, const float* __restrict__ dinv,
    _Float16* __restrict__ out, int ldo)
{
    __shared__ __align__(16) _Float16 As[128][64 + LDS_PAD];
    __shared__ __align__(16) _Float16 Bs[128][64 + LDS_PAD];
    __shared__ float SS[2 * K];
    const int row0 = blockIdx.x * 128;
    const int col0 = blockIdx.y * 128;
    const int tid = threadIdx.x;
    if (XFORM) {
        for (int i = tid; i < 2 * K; i += 256) SS[i] = ss[i];
    }
    const int lane = tid & 63;
    const int wv = tid >> 6;
    const int wr = wv >> 1, wc = wv & 1;
    const int fr = lane & 15;
    const int kb = (lane >> 4) * 8;

    f32x4 acc[4][4];
    #pragma unroll
    for (int m = 0; m < 4; ++m)
        #pragma unroll
        for (int n = 0; n < 4; ++n)
            acc[m][n] = (f32x4){0.f, 0.f, 0.f, 0.f};

    if (XFORM) __syncthreads();

    for (int k0 = 0; k0 < K; k0 += 64) {
        // stage A: 128x64 halves, 4 chunks of h8 per thread
        #pragma unroll
        for (int p = 0; p < 4; ++p) {
            int c = p * 256 + tid;
            int m = c >> 3, kk = (c & 7) * 8;
            int r = row0 + m;
            h8 av = {};
            if (r < NN) av = *(const h8*)&A[(size_t)r * lda + k0 + kk];
            if (XFORM) {
                #pragma unroll
                for (int j = 0; j < 8; ++j) {
                    float a = (float)av[j];
                    a = fmaxf(fmaf(a, SS[k0 + kk + j], SS[K + k0 + kk + j]), 0.0f);
                    av[j] = (_Float16)a;
                }
            }
            *(h8*)&As[m][kk] = av;
        }
        // stage B: 128x64 halves
        #pragma unroll
        for (int p = 0; p < 4; ++p) {
            int c = p * 256 + tid;
            int n = c >> 3, kk = (c & 7) * 8;
            h8 bv = *(const h8*)&Wt[(size_t)(col0 + n) * K + k0 + kk];
            *(h8*)&Bs[n][kk] = bv;
        }
        __syncthreads();
        #pragma unroll
        for (int ks = 0; ks < 2; ++ks) {
            h8 a[4], b[4];
            #pragma unroll
            for (int m = 0; m < 4; ++m)
                a[m] = *(const h8*)&As[wr * 64 + m * 16 + fr][ks * 32 + kb];
            #pragma unroll
            for (int n = 0; n < 4; ++n)
                b[n] = *(const h8*)&Bs[wc * 64 + n * 16 + fr][ks * 32 + kb];
            #pragma unroll
            for (int m = 0; m < 4; ++m)
                #pragma unroll
                for (int n = 0; n < 4; ++n)
                    acc[m][n] = __builtin_amdgcn_mfma_f32_16x16x32_f16(a[m], b[n], acc[m][n], 0, 0, 0);
        }
        __syncthreads();
    }

    const int fq = lane >> 4;
    #pragma unroll
    for (int m = 0; m < 4; ++m) {
        #pragma unroll
        for (int j = 0; j < 4; ++j) {
            int r = row0 + wr * 64 + m * 16 + fq * 4 + j;
            if (r >= NN) continue;
            float dv = EPI_DINV ? dinv[r] : 1.0f;
            #pragma unroll
            for (int n = 0; n < 4; ++n) {
                int c = col0 + wc * 64 + n * 16 + fr;
                out[(size_t)r * ldo + c] = (_Float16)(acc[m][n][j] * dv);
            }
        }
    }
}

// ---------------- narrow MFMA GEMM for layer 2 (BN=64), as before ----------------

template<int K, bool XFORM, bool EPI_DINV>
__global__ __launch_bounds__(256) void mfma_gemm_kernel(
    const _Float16* __restrict__ A, int lda,
    const _Float16* __restrict__ Wt,
    const float* __restrict__ ss, const float* __restrict__ dinv,
    _Float16* __restrict__ out, int ldo, int ncolsO)
{
    __shared__ __align__(16) _Float16 As[128][32 + LDS_PAD];
    __shared__ __align__(16) _Float16 Bs[64][32 + LDS_PAD];
    __shared__ float SS[2 * K];
    const int row0 = blockIdx.x * 128;
    const int col0 = blockIdx.y * 64;
    const int tid = threadIdx.x;
    if (XFORM) {
        for (int i = tid; i < 2 * K; i += 256) SS[i] = ss[i];
    }
    const int lane = tid & 63;
    const int wv = tid >> 6;
    const int wr = wv >> 1, wc = wv & 1;
    const int fr = lane & 15;
    const int kb = (lane >> 4) * 8;

    f32x4 acc[4][2];
    #pragma unroll
    for (int m = 0; m < 4; ++m)
        #pragma unroll
        for (int n = 0; n < 2; ++n)
            acc[m][n] = (f32x4){0.f, 0.f, 0.f, 0.f};

    if (XFORM) __syncthreads();

    for (int k0 = 0; k0 < K; k0 += 32) {
        #pragma unroll
        for (int p = 0; p < 2; ++p) {
            int idx = (p * 256 + tid) * 8;
            int m = idx >> 5, kk = idx & 31;
            int r = row0 + m;
            h8 av = {};
            if (r < NN) av = *(const h8*)&A[(size_t)r * lda + k0 + kk];
            if (XFORM) {
                #pragma unroll
                for (int j = 0; j < 8; ++j) {
                    float a = (float)av[j];
                    a = fmaxf(fmaf(a, SS[k0 + kk + j], SS[K + k0 + kk + j]), 0.0f);
                    av[j] = (_Float16)a;
                }
            }
            *(h8*)&As[m][kk] = av;
        }
        {
            int idx = tid * 8;
            int n = idx >> 5, kk = idx & 31;
            h8 bv = *(const h8*)&Wt[(size_t)(col0 + n) * K + k0 + kk];
            *(h8*)&Bs[n][kk] = bv;
        }
        __syncthreads();
        h8 a[4], b[2];
        #pragma unroll
        for (int m = 0; m < 4; ++m)
            a[m] = *(const h8*)&As[wr * 64 + m * 16 + fr][kb];
        #pragma unroll
        for (int n = 0; n < 2; ++n)
            b[n] = *(const h8*)&Bs[wc * 32 + n * 16 + fr][kb];
        #pragma unroll
        for (int m = 0; m < 4; ++m)
            #pragma unroll
            for (int n = 0; n < 2; ++n)
                acc[m][n] = __builtin_amdgcn_mfma_f32_16x16x32_f16(a[m], b[n], acc[m][n], 0, 0, 0);
        __syncthreads();
    }

    const int fq = lane >> 4;
    #pragma unroll
    for (int m = 0; m < 4; ++m) {
        #pragma unroll
        for (int j = 0; j < 4; ++j) {
            int r = row0 + wr * 64 + m * 16 + fq * 4 + j;
            if (r >= NN) continue;
            float dv = EPI_DINV ? dinv[r] : 1.0f;
            #pragma unroll
            for (int n = 0; n < 2; ++n) {
                int c = col0 + wc * 32 + n * 16 + fr;
                if (c < ncolsO) out[(size_t)r * ldo + c] = (_Float16)(acc[m][n][j] * dv);
            }
        }
    }
}

// ---------------- BatchNorm stats: vectorized partials + fused reduce/finalize ----

__global__ __launch_bounds__(256) void bn_part_kernel(const _Float16* __restrict__ h,
                                                      float* __restrict__ part) {
    int tid = threadIdx.x;
    int fg = tid & 63;          // feature group of 4
    int rg = tid >> 6;          // row group 0..3
    float s1[4] = {}, s2[4] = {};
    for (int r = blockIdx.x * 4 + rg; r < NN; r += 4096) {
        h4 v = ((const h4*)(h + (size_t)r * HD))[fg];
        #pragma unroll
        for (int j = 0; j < 4; ++j) {
            float f = (float)v[j];
            s1[j] += f; s2[j] += f * f;
        }
    }
    __shared__ float sm[256][8];
    #pragma unroll
    for (int j = 0; j < 4; ++j) { sm[tid][j] = s1[j]; sm[tid][4 + j] = s2[j]; }
    __syncthreads();
    if (tid < 64) {
        float o1[4] = {}, o2[4] = {};
        #pragma unroll
        for (int r = 0; r < 4; ++r)
            #pragma unroll
            for (int j = 0; j < 4; ++j) {
                o1[j] += sm[r * 64 + tid][j];
                o2[j] += sm[r * 64 + tid][4 + j];
            }
        #pragma unroll
        for (int j = 0; j < 4; ++j) {
            part[(size_t)blockIdx.x * 512 + tid * 4 + j] = o1[j];
            part[(size_t)blockIdx.x * 512 + 256 + tid * 4 + j] = o2[j];
        }
    }
}

__global__ __launch_bounds__(256) void bn_reduce_kernel(const float* __restrict__ part,
                                                        const float* __restrict__ g,
                                                        const float* __restrict__ be,
                                                        float* __restrict__ ss) {
    int f = blockIdx.x * 32 + (threadIdx.x & 31);
    int c = threadIdx.x >> 5;   // 0..7
    float s1 = 0.f, s2 = 0.f;
    for (int b = c; b < 1024; b += 8) {
        s1 += part[(size_t)b * 512 + f];
        s2 += part[(size_t)b * 512 + 256 + f];
    }
    __shared__ float m1[8][32], m2[8][32];
    m1[c][threadIdx.x & 31] = s1; m2[c][threadIdx.x & 31] = s2;
    __syncthreads();
    if (threadIdx.x < 32) {
        float t1 = 0.f, t2 = 0.f;
        #pragma unroll
        for (int q = 0; q < 8; ++q) { t1 += m1[q][threadIdx.x]; t2 += m2[q][threadIdx.x]; }
        float mean = t1 * (1.0f / NN);
        float var = t2 * (1.0f / NN) - mean * mean;
        float sc = g[f] * rsqrtf(var + 1e-5f);
        ss[f] = sc;
        ss[HD + f] = be[f] - mean * sc;
    }
}

// ---------------- launch ----------------

extern "C" void kernel_launch(void* const* d_in, const int* in_sizes, int n_in,
                              void* d_out, int out_size, void* d_ws, size_t ws_size,
                              hipStream_t stream) {
    const float* x   = (const float*)d_in[0];
    const int*   ei  = (const int*)d_in[1];
    const float* W0  = (const float*)d_in[3];
    const float* g0  = (const float*)d_in[5];
    const float* be0 = (const float*)d_in[6];
    const float* W1  = (const float*)d_in[7];
    const float* g1  = (const float*)d_in[9];
    const float* be1 = (const float*)d_in[10];
    const float* W2  = (const float*)d_in[11];
    const float* b2  = (const float*)d_in[12];
    float* out = (float*)d_out;

    const int* src = ei;            // edge_index[0]
    const int* dst = ei + NE;       // edge_index[1]

    const size_t S = 51200000;                        // 100000*256*2 bytes
    char* ws = (char*)d_ws;
    _Float16* S1   = (_Float16*)ws;                   // t1 / t2 slot
    unsigned* xq   = (unsigned*)ws;                   // [NN][128] fp8 (12.8MB)
    _Float16* a0   = (_Float16*)(ws + 12800000);      // [NN][128] fp16 (25.6MB)
    _Float16* S2   = (_Float16*)(ws + S);             // h0 / h1 slot
    char* base2 = ws + 2 * S;
    int*   csr  = (int*)  (base2);                    // 12.8MB
    int*   offs = (int*)  (base2 + 12800000);
    float* dinv = (float*)(base2 + 13200064);
    float* ssb  = (float*)(base2 + 13602112);
    int*   bsum = (int*)  (base2 + 13604160);
    _Float16* wt0 = (_Float16*)(base2 + 13608320);    // [256][128]
    _Float16* wt1 = (_Float16*)(base2 + 13673856);    // [256][256]
    _Float16* wt2 = (_Float16*)(base2 + 13804928);    // [64][256]
    int*   hist = (int*)  (base2 + 13837696);         // NBKT*G+1 ints
    int*   epk  = (int*)  (base2 + 14640576);         // NE ints = 12.8MB
    float* part = (float*)(base2 + 27440576);         // 1024*512 floats = 2MB

    // CSR build: bucketed counting sort
    const int N2 = NBKT * G;
    const int NB2 = (N2 + 255) / 256;
    hist_kernel<<<G, 256, 0, stream>>>(dst, hist);
    scan1_kernel<<<NB2, 256, 0, stream>>>(hist, hist, bsum, N2);
    scan2_kernel<<<1, 1024, 0, stream>>>(bsum, NB2);
    scan3_kernel<<<NB2, 256, 0, stream>>>(hist, bsum, NB2, N2);
    scatter_kernel<<<G, 256, 0, stream>>>(src, dst, hist, epk);
    bucket_fill_kernel<<<NBKT, 256, 0, stream>>>(hist, epk, csr, offs, dinv);

    // weights -> fp16 transposed
    wtrans_kernel<FIN><<<(256 * FIN + 255) / 256, 256, 0, stream>>>(W0, wt0, HD, HD);
    wtrans_kernel<HD><<<(256 * HD + 255) / 256, 256, 0, stream>>>(W1, wt1, HD, HD);
    wtrans_kernel<HD><<<(COP * HD + 255) / 256, 256, 0, stream>>>(W2, wt2, CO, COP);

    const int MB = (NN + 127) / 128;   // 782

    // Layer 0 (reassociated): a0 = D^-1/2 (A+I) D^-1/2 x (fp8 gather); h0 = a0 @ W0
    conv_x_kernel<<<(NN * FIN / 4 + 255) / 256, 256, 0, stream>>>(x, dinv, xq);
    agg128_kernel<<<NN / 4, 256, 0, stream>>>((const unsigned short*)xq, offs, csr, dinv, a0);
    mfma_gemm_big<FIN, false, false><<<dim3(MB, 2), 256, 0, stream>>>(
        a0, FIN, wt0, nullptr, dinv, S2, HD);                   // h0 -> S2

    bn_part_kernel<<<1024, 256, 0, stream>>>(S2, part);
    bn_reduce_kernel<<<8, 256, 0, stream>>>(part, g0, be0, ssb);

    // Layer 1: t1 = dinv * (relu(bn(h0)) @ W1); h1 = dinv*(A+I)t1
    mfma_gemm_big<HD, true, true><<<dim3(MB, 2), 256, 0, stream>>>(
        S2, HD, wt1, ssb, dinv, S1, HD);                        // t1 -> S1
    agg256_kernel<<<NN / 4, 256, 0, stream>>>(S1, offs, csr, dinv, S2);  // h1 -> S2

    bn_part_kernel<<<1024, 256, 0, stream>>>(S2, part);
    bn_reduce_kernel<<<8, 256, 0, stream>>>(part, g1, be1, ssb);

    // Layer 2: t2 = dinv * (relu(bn(h1)) @ W2), rows padded to 64; agg + log_softmax
    mfma_gemm_kernel<HD, true, true><<<dim3(MB, 1), 256, 0, stream>>>(
        S2, HD, wt2, ssb, dinv, S1, COP, COP);                  // t2 -> S1
    agg47_lsm_kernel<<<NN / 4, 256, 0, stream>>>(S1, offs, csr, dinv, b2, out);
}

// Round 8
// 687.175 us; speedup vs baseline: 1.0476x; 1.0476x over previous
//
#include <hip/hip_runtime.h>
#include <hip/hip_fp8.h>
#include <math.h>

#define NN 100000
#define NE 3200000
#define FIN 128
#define HD 256
#define CO 47
#define COP 48     // t2 row stride (fp16) for layer-2 gather
#define NBKT 196   // buckets of 512 nodes: dst>>9
#define G 1024     // partition blocks
#define CHUNK 3125 // NE / G exactly

typedef _Float16 h2 __attribute__((ext_vector_type(2)));
typedef _Float16 h4 __attribute__((ext_vector_type(4)));
typedef _Float16 h8 __attribute__((ext_vector_type(8)));
typedef float f32x4 __attribute__((ext_vector_type(4)));

// ---------------- CSR build via bucketed counting sort ----------------

__global__ __launch_bounds__(256) void hist_kernel(const int* __restrict__ dst,
                                                   int* __restrict__ hist) {
    __shared__ int h[NBKT];
    int tid = threadIdx.x;
    for (int i = tid; i < NBKT; i += 256) h[i] = 0;
    __syncthreads();
    int base = blockIdx.x * CHUNK;
    for (int i = tid; i < CHUNK; i += 256)
        atomicAdd(&h[dst[base + i] >> 9], 1);
    __syncthreads();
    for (int i = tid; i < NBKT; i += 256) hist[i * G + blockIdx.x] = h[i];
}

__global__ void scan1_kernel(const int* __restrict__ in, int* __restrict__ out,
                             int* __restrict__ bsum, int n) {
    __shared__ int tmp[256];
    int t = threadIdx.x;
    int i = blockIdx.x * 256 + t;
    int v = (i < n) ? in[i] : 0;
    tmp[t] = v;
    __syncthreads();
    #pragma unroll
    for (int off = 1; off < 256; off <<= 1) {
        int u = (t >= off) ? tmp[t - off] : 0;
        __syncthreads();
        tmp[t] += u;
        __syncthreads();
    }
    if (i < n) out[i] = tmp[t] - v;
    if (t == 255) bsum[blockIdx.x] = tmp[255];
}

__global__ void scan2_kernel(int* __restrict__ bsum, int nb) {
    __shared__ int tmp[1024];
    int t = threadIdx.x;
    int v = (t < nb) ? bsum[t] : 0;
    tmp[t] = v;
    __syncthreads();
    #pragma unroll
    for (int off = 1; off < 1024; off <<= 1) {
        int u = (t >= off) ? tmp[t - off] : 0;
        __syncthreads();
        tmp[t] += u;
        __syncthreads();
    }
    if (t < nb) bsum[t] = tmp[t] - v;
    if (t == nb - 1) bsum[nb] = tmp[t];
}

__global__ void scan3_kernel(int* __restrict__ out, const int* __restrict__ bsum,
                             int nb, int n) {
    int i = blockIdx.x * 256 + threadIdx.x;
    if (i < n) out[i] += bsum[i >> 8];
    if (i == 0) out[n] = bsum[nb];
}

__global__ __launch_bounds__(256) void scatter_kernel(const int* __restrict__ src,
                                                      const int* __restrict__ dst,
                                                      const int* __restrict__ hscan,
                                                      int* __restrict__ epk) {
    __shared__ int cur[NBKT];
    int tid = threadIdx.x;
    for (int i = tid; i < NBKT; i += 256) cur[i] = hscan[i * G + blockIdx.x];
    __syncthreads();
    int base = blockIdx.x * CHUNK;
    for (int i = tid; i < CHUNK; i += 256) {
        int e = base + i;
        int d = dst[e];
        int slot = atomicAdd(&cur[d >> 9], 1);
        epk[slot] = ((d & 511) << 17) | src[e];
    }
}

__global__ __launch_bounds__(256) void bucket_fill_kernel(
    const int* __restrict__ hscan, const int* __restrict__ epk,
    int* __restrict__ csr, int* __restrict__ offs, float* __restrict__ dinv)
{
    __shared__ int deg[512], cur[512], a0[512], a1[512];
    int tid = threadIdx.x, b = blockIdx.x;
    int ebeg = hscan[b * G], eend = hscan[(b + 1) * G];
    deg[tid] = 0; deg[tid + 256] = 0;
    __syncthreads();
    for (int e = ebeg + tid; e < eend; e += 256)
        atomicAdd(&deg[((unsigned)epk[e]) >> 17], 1);
    __syncthreads();
    a0[tid] = deg[tid]; a0[tid + 256] = deg[tid + 256];
    __syncthreads();
    int* pin = a0; int* pout = a1;
    for (int off = 1; off < 512; off <<= 1) {
        #pragma unroll
        for (int q = 0; q < 2; ++q) {
            int p = tid + q * 256;
            pout[p] = pin[p] + ((p >= off) ? pin[p - off] : 0);
        }
        __syncthreads();
        int* t = pin; pin = pout; pout = t;
    }
    #pragma unroll
    for (int q = 0; q < 2; ++q) {
        int i = tid + q * 256;
        int excl = pin[i] - deg[i];
        cur[i] = excl;
        int node = b * 512 + i;
        if (node < NN) {
            offs[node] = ebeg + excl;
            dinv[node] = rsqrtf((float)deg[i] + 1.0f);
        }
    }
    if (b == 0 && tid == 0) offs[NN] = NE;
    __syncthreads();
    for (int e = ebeg + tid; e < eend; e += 256) {
        int pk = epk[e];
        int p = atomicAdd(&cur[((unsigned)pk) >> 17], 1);
        csr[ebeg + p] = pk & 0x1FFFF;
    }
}

// ---------------- weight convert ----------------

template<int K>
__global__ void wtrans_kernel(const float* __restrict__ W, _Float16* __restrict__ Wt,
                              int N, int NP) {
    int i = blockIdx.x * 256 + threadIdx.x;
    if (i >= NP * K) return;
    int n = i / K, k = i % K;
    float v = (n < N) ? W[(size_t)k * N + n] : 0.0f;
    Wt[i] = (_Float16)v;
}

// ---------------- x -> fp8 e4m3 (OCP), pre-scaled by dinv ----------------

__global__ void conv_x_kernel(const float* __restrict__ x, const float* __restrict__ dinv,
                              unsigned* __restrict__ xq) {
    int i = blockIdx.x * 256 + threadIdx.x;     // over NN*FIN/4
    if (i >= NN * FIN / 4) return;
    int r = i >> 5;
    float4 v = ((const float4*)x)[i];
    float dv = dinv[r];
    __hip_fp8_e4m3 q0(v.x * dv), q1(v.y * dv), q2(v.z * dv), q3(v.w * dv);
    unsigned u = (unsigned)q0.__x | ((unsigned)q1.__x << 8) |
                 ((unsigned)q2.__x << 16) | ((unsigned)q3.__x << 24);
    xq[i] = u;
}

// decode OCP e4m3fn -> float (exact, incl. subnormals): fp16(bits=(u&0x7f)<<7) * 256
__device__ inline float dec8(unsigned u) {
    unsigned short hb = (unsigned short)((u & 0x7Fu) << 7);
    float f = (float)__builtin_bit_cast(_Float16, hb) * 256.0f;
    unsigned fb = __builtin_bit_cast(unsigned, f) ^ ((u & 0x80u) << 24);
    return __builtin_bit_cast(float, fb);
}

// ---------------- aggregation (wave per node, atomic-free) ----------------

__global__ __launch_bounds__(256) void agg128_kernel(
    const unsigned short* __restrict__ xq, const int* __restrict__ offs,
    const int* __restrict__ csr, const float* __restrict__ dinv,
    _Float16* __restrict__ out)
{
    int lane = threadIdx.x & 63;
    int v = blockIdx.x * 4 + (threadIdx.x >> 6);
    unsigned sv = xq[(size_t)v * 64 + lane];    // 2 fp8 per lane
    float ax = dec8(sv & 0xFF), ay = dec8(sv >> 8);
    int b = offs[v], e = offs[v + 1], j = b;
    int s[8];
    if (j + 8 <= e) {
        #pragma unroll
        for (int q = 0; q < 8; ++q) s[q] = csr[j + q];
    }
    for (; j + 8 <= e; ) {
        int nj = j + 8;
        int ns[8];
        if (nj + 8 <= e) {
            #pragma unroll
            for (int q = 0; q < 8; ++q) ns[q] = csr[nj + q];
        }
        #pragma unroll
        for (int q = 0; q < 8; ++q) {
            unsigned t = xq[(size_t)s[q] * 64 + lane];
            ax += dec8(t & 0xFF); ay += dec8(t >> 8);
        }
        #pragma unroll
        for (int q = 0; q < 8; ++q) s[q] = ns[q];
        j = nj;
    }
    for (; j < e; ++j) {
        unsigned t = xq[(size_t)csr[j] * 64 + lane];
        ax += dec8(t & 0xFF); ay += dec8(t >> 8);
    }
    float dv = dinv[v];
    h2 o; o[0] = (_Float16)(ax * dv); o[1] = (_Float16)(ay * dv);
    ((h2*)out)[(size_t)v * 64 + lane] = o;
}

// t1 is fp8: 256 B rows, 64 u32/lane-row; fp32 accumulate; fp16 out (h1)
__global__ __launch_bounds__(256) void agg256_kernel(
    const unsigned* __restrict__ t1q, const int* __restrict__ offs,
    const int* __restrict__ csr, const float* __restrict__ dinv,
    _Float16* __restrict__ out)
{
    int lane = threadIdx.x & 63;
    int v = blockIdx.x * 4 + (threadIdx.x >> 6);
    unsigned sv = t1q[(size_t)v * 64 + lane];   // 4 fp8 per lane
    float a0 = dec8(sv & 0xFF), a1 = dec8((sv >> 8) & 0xFF);
    float a2 = dec8((sv >> 16) & 0xFF), a3 = dec8(sv >> 24);
    int b = offs[v], e = offs[v + 1], j = b;
    int s[8];
    if (j + 8 <= e) {
        #pragma unroll
        for (int q = 0; q < 8; ++q) s[q] = csr[j + q];
    }
    for (; j + 8 <= e; ) {
        int nj = j + 8;
        int ns[8];
        if (nj + 8 <= e) {
            #pragma unroll
            for (int q = 0; q < 8; ++q) ns[q] = csr[nj + q];
        }
        #pragma unroll
        for (int q = 0; q < 8; ++q) {
            unsigned t = t1q[(size_t)s[q] * 64 + lane];
            a0 += dec8(t & 0xFF); a1 += dec8((t >> 8) & 0xFF);
            a2 += dec8((t >> 16) & 0xFF); a3 += dec8(t >> 24);
        }
        #pragma unroll
        for (int q = 0; q < 8; ++q) s[q] = ns[q];
        j = nj;
    }
    for (; j < e; ++j) {
        unsigned t = t1q[(size_t)csr[j] * 64 + lane];
        a0 += dec8(t & 0xFF); a1 += dec8((t >> 8) & 0xFF);
        a2 += dec8((t >> 16) & 0xFF); a3 += dec8(t >> 24);
    }
    float dv = dinv[v];
    h4 o; o[0] = (_Float16)(a0 * dv); o[1] = (_Float16)(a1 * dv);
    o[2] = (_Float16)(a2 * dv); o[3] = (_Float16)(a3 * dv);
    ((h4*)out)[(size_t)v * 64 + lane] = o;
}

__global__ __launch_bounds__(256) void agg47_lsm_kernel(
    const _Float16* __restrict__ t2, const int* __restrict__ offs,
    const int* __restrict__ csr, const float* __restrict__ dinv,
    const float* __restrict__ bias, float* __restrict__ out)
{
    int lane = threadIdx.x & 63;
    int v = blockIdx.x * 4 + (threadIdx.x >> 6);
    bool act = lane < CO;
    float acc = act ? (float)t2[(size_t)v * COP + lane] : 0.0f;
    int b = offs[v], e = offs[v + 1], j = b;
    int s[8];
    if (j + 8 <= e) {
        #pragma unroll
        for (int q = 0; q < 8; ++q) s[q] = csr[j + q];
    }
    for (; j + 8 <= e; ) {
        int nj = j + 8;
        int ns[8];
        if (nj + 8 <= e) {
            #pragma unroll
            for (int q = 0; q < 8; ++q) ns[q] = csr[nj + q];
        }
        if (act) {
            #pragma unroll
            for (int q = 0; q < 8; ++q) acc += (float)t2[(size_t)s[q] * COP + lane];
        }
        #pragma unroll
        for (int q = 0; q < 8; ++q) s[q] = ns[q];
        j = nj;
    }
    for (; j < e; ++j) if (act) acc += (float)t2[(size_t)csr[j] * COP + lane];
    float val = act ? fmaf(acc, dinv[v], bias[lane]) : -1e30f;
    float m = val;
    #pragma unroll
    for (int o = 32; o > 0; o >>= 1) m = fmaxf(m, __shfl_xor(m, o, 64));
    float ex = act ? expf(val - m) : 0.0f;
    float sum = ex;
    #pragma unroll
    for (int o = 32; o > 0; o >>= 1) sum += __shfl_xor(sum, o, 64);
    if (act) out[(size_t)v * CO + lane] = val - m - logf(sum);
}

// ---------------- big MFMA GEMM: BM=128, BN=128, BK=64, 4 waves (2x2), 64x64/wave ----

#define LDS_PAD 8

template<int K, bool XFORM, bool EPI_DINV, bool OUT8>
__global__ __launch_bounds__(256) void mfma_gemm_big(
    const _Float16* __restrict__ A, int lda,
    const _Float16* __restrict__ Wt,
    const float* __restrict__ ss, const float* __restrict__ dinv,
    void* __restrict__ outp, int ldo)
{
    __shared__ __align__(16) _Float16 As[128][64 + LDS_PAD];
    __shared__ __align__(16) _Float16 Bs[128][64 + LDS_PAD];
    __shared__ float SS[2 * K];
    const int row0 = blockIdx.x * 128;
    const int col0 = blockIdx.y * 128;
    const int tid = threadIdx.x;
    if (XFORM) {
        for (int i = tid; i < 2 * K; i += 256) SS[i] = ss[i];
    }
    const int lane = tid & 63;
    const int wv = tid >> 6;
    const int wr = wv >> 1, wc = wv & 1;
    const int fr = lane & 15;
    const int kb = (lane >> 4) * 8;

    f32x4 acc[4][4];
    #pragma unroll
    for (int m = 0; m < 4; ++m)
        #pragma unroll
        for (int n = 0; n < 4; ++n)
            acc[m][n] = (f32x4){0.f, 0.f, 0.f, 0.f};

    if (XFORM) __syncthreads();

    for (int k0 = 0; k0 < K; k0 += 64) {
        #pragma unroll
        for (int p = 0; p < 4; ++p) {
            int c = p * 256 + tid;
            int m = c >> 3, kk = (c & 7) * 8;
            int r = row0 + m;
            h8 av = {};
            if (r < NN) av = *(const h8*)&A[(size_t)r * lda + k0 + kk];
            if (XFORM) {
                #pragma unroll
                for (int j = 0; j < 8; ++j) {
                    float a = (float)av[j];
                    a = fmaxf(fmaf(a, SS[k0 + kk + j], SS[K + k0 + kk + j]), 0.0f);
                    av[j] = (_Float16)a;
                }
            }
            *(h8*)&As[m][kk] = av;
        }
        #pragma unroll
        for (int p = 0; p < 4; ++p) {
            int c = p * 256 + tid;
            int n = c >> 3, kk = (c & 7) * 8;
            h8 bv = *(const h8*)&Wt[(size_t)(col0 + n) * K + k0 + kk];
            *(h8*)&Bs[n][kk] = bv;
        }
        __syncthreads();
        #pragma unroll
        for (int ks = 0; ks < 2; ++ks) {
            h8 a[4], b[4];
            #pragma unroll
            for (int m = 0; m < 4; ++m)
                a[m] = *(const h8*)&As[wr * 64 + m * 16 + fr][ks * 32 + kb];
            #pragma unroll
            for (int n = 0; n < 4; ++n)
                b[n] = *(const h8*)&Bs[wc * 64 + n * 16 + fr][ks * 32 + kb];
            #pragma unroll
            for (int m = 0; m < 4; ++m)
                #pragma unroll
                for (int n = 0; n < 4; ++n)
                    acc[m][n] = __builtin_amdgcn_mfma_f32_16x16x32_f16(a[m], b[n], acc[m][n], 0, 0, 0);
        }
        __syncthreads();
    }

    const int fq = lane >> 4;
    #pragma unroll
    for (int m = 0; m < 4; ++m) {
        #pragma unroll
        for (int j = 0; j < 4; ++j) {
            int r = row0 + wr * 64 + m * 16 + fq * 4 + j;
            if (r >= NN) continue;
            float dv = EPI_DINV ? dinv[r] : 1.0f;
            #pragma unroll
            for (int n = 0; n < 4; ++n) {
                int c = col0 + wc * 64 + n * 16 + fr;
                float val = acc[m][n][j] * dv;
                if (OUT8) {
                    ((unsigned char*)outp)[(size_t)r * ldo + c] = __hip_fp8_e4m3(val).__x;
                } else {
                    ((_Float16*)outp)[(size_t)r * ldo + c] = (_Float16)val;
                }
            }
        }
    }
}

// ---------------- narrow MFMA GEMM for layer 2 (BN=64 cols) ----------------

template<int K, bool XFORM, bool EPI_DINV>
__global__ __launch_bounds__(256) void mfma_gemm_kernel(
    const _Float16* __restrict__ A, int lda,
    const _Float16* __restrict__ Wt,
    const float* __restrict__ ss, const float* __restrict__ dinv,
    _Float16* __restrict__ out, int ldo, int ncolsO)
{
    __shared__ __align__(16) _Float16 As[128][32 + LDS_PAD];
    __shared__ __align__(16) _Float16 Bs[64][32 + LDS_PAD];
    __shared__ float SS[2 * K];
    const int row0 = blockIdx.x * 128;
    const int col0 = blockIdx.y * 64;
    const int tid = threadIdx.x;
    if (XFORM) {
        for (int i = tid; i < 2 * K; i += 256) SS[i] = ss[i];
    }
    const int lane = tid & 63;
    const int wv = tid >> 6;
    const int wr = wv >> 1, wc = wv & 1;
    const int fr = lane & 15;
    const int kb = (lane >> 4) * 8;

    f32x4 acc[4][2];
    #pragma unroll
    for (int m = 0; m < 4; ++m)
        #pragma unroll
        for (int n = 0; n < 2; ++n)
            acc[m][n] = (f32x4){0.f, 0.f, 0.f, 0.f};

    if (XFORM) __syncthreads();

    for (int k0 = 0; k0 < K; k0 += 32) {
        #pragma unroll
        for (int p = 0; p < 2; ++p) {
            int idx = (p * 256 + tid) * 8;
            int m = idx >> 5, kk = idx & 31;
            int r = row0 + m;
            h8 av = {};
            if (r < NN) av = *(const h8*)&A[(size_t)r * lda + k0 + kk];
            if (XFORM) {
                #pragma unroll
                for (int j = 0; j < 8; ++j) {
                    float a = (float)av[j];
                    a = fmaxf(fmaf(a, SS[k0 + kk + j], SS[K + k0 + kk + j]), 0.0f);
                    av[j] = (_Float16)a;
                }
            }
            *(h8*)&As[m][kk] = av;
        }
        {
            int idx = tid * 8;
            int n = idx >> 5, kk = idx & 31;
            h8 bv = *(const h8*)&Wt[(size_t)(col0 + n) * K + k0 + kk];
            *(h8*)&Bs[n][kk] = bv;
        }
        __syncthreads();
        h8 a[4], b[2];
        #pragma unroll
        for (int m = 0; m < 4; ++m)
            a[m] = *(const h8*)&As[wr * 64 + m * 16 + fr][kb];
        #pragma unroll
        for (int n = 0; n < 2; ++n)
            b[n] = *(const h8*)&Bs[wc * 32 + n * 16 + fr][kb];
        #pragma unroll
        for (int m = 0; m < 4; ++m)
            #pragma unroll
            for (int n = 0; n < 2; ++n)
                acc[m][n] = __builtin_amdgcn_mfma_f32_16x16x32_f16(a[m], b[n], acc[m][n], 0, 0, 0);
        __syncthreads();
    }

    const int fq = lane >> 4;
    #pragma unroll
    for (int m = 0; m < 4; ++m) {
        #pragma unroll
        for (int j = 0; j < 4; ++j) {
            int r = row0 + wr * 64 + m * 16 + fq * 4 + j;
            if (r >= NN) continue;
            float dv = EPI_DINV ? dinv[r] : 1.0f;
            #pragma unroll
            for (int n = 0; n < 2; ++n) {
                int c = col0 + wc * 32 + n * 16 + fr;
                if (c < ncolsO) out[(size_t)r * ldo + c] = (_Float16)(acc[m][n][j] * dv);
            }
        }
    }
}

// ---------------- BatchNorm stats: vectorized partials + fused reduce/finalize ----

__global__ __launch_bounds__(256) void bn_part_kernel(const _Float16* __restrict__ h,
                                                      float* __restrict__ part) {
    int tid = threadIdx.x;
    int fg = tid & 63;
    int rg = tid >> 6;
    float s1[4] = {}, s2[4] = {};
    for (int r = blockIdx.x * 4 + rg; r < NN; r += 4096) {
        h4 v = ((const h4*)(h + (size_t)r * HD))[fg];
        #pragma unroll
        for (int j = 0; j < 4; ++j) {
            float f = (float)v[j];
            s1[j] += f; s2[j] += f * f;
        }
    }
    __shared__ float sm[256][8];
    #pragma unroll
    for (int j = 0; j < 4; ++j) { sm[tid][j] = s1[j]; sm[tid][4 + j] = s2[j]; }
    __syncthreads();
    if (tid < 64) {
        float o1[4] = {}, o2[4] = {};
        #pragma unroll
        for (int r = 0; r < 4; ++r)
            #pragma unroll
            for (int j = 0; j < 4; ++j) {
                o1[j] += sm[r * 64 + tid][j];
                o2[j] += sm[r * 64 + tid][4 + j];
            }
        #pragma unroll
        for (int j = 0; j < 4; ++j) {
            part[(size_t)blockIdx.x * 512 + tid * 4 + j] = o1[j];
            part[(size_t)blockIdx.x * 512 + 256 + tid * 4 + j] = o2[j];
        }
    }
}

__global__ __launch_bounds__(256) void bn_reduce_kernel(const float* __restrict__ part,
                                                        const float* __restrict__ g,
                                                        const float* __restrict__ be,
                                                        float* __restrict__ ss) {
    int f = blockIdx.x * 32 + (threadIdx.x & 31);
    int c = threadIdx.x >> 5;
    float s1 = 0.f, s2 = 0.f;
    for (int b = c; b < 1024; b += 8) {
        s1 += part[(size_t)b * 512 + f];
        s2 += part[(size_t)b * 512 + 256 + f];
    }
    __shared__ float m1[8][32], m2[8][32];
    m1[c][threadIdx.x & 31] = s1; m2[c][threadIdx.x & 31] = s2;
    __syncthreads();
    if (threadIdx.x < 32) {
        float t1 = 0.f, t2 = 0.f;
        #pragma unroll
        for (int q = 0; q < 8; ++q) { t1 += m1[q][threadIdx.x]; t2 += m2[q][threadIdx.x]; }
        float mean = t1 * (1.0f / NN);
        float var = t2 * (1.0f / NN) - mean * mean;
        float sc = g[f] * rsqrtf(var + 1e-5f);
        ss[f] = sc;
        ss[HD + f] = be[f] - mean * sc;
    }
}

// ---------------- launch ----------------

extern "C" void kernel_launch(void* const* d_in, const int* in_sizes, int n_in,
                              void* d_out, int out_size, void* d_ws, size_t ws_size,
                              hipStream_t stream) {
    const float* x   = (const float*)d_in[0];
    const int*   ei  = (const int*)d_in[1];
    const float* W0  = (const float*)d_in[3];
    const float* g0  = (const float*)d_in[5];
    const float* be0 = (const float*)d_in[6];
    const float* W1  = (const float*)d_in[7];
    const float* g1  = (const float*)d_in[9];
    const float* be1 = (const float*)d_in[10];
    const float* W2  = (const float*)d_in[11];
    const float* b2  = (const float*)d_in[12];
    float* out = (float*)d_out;

    const int* src = ei;            // edge_index[0]
    const int* dst = ei + NE;       // edge_index[1]

    const size_t S = 51200000;                        // 100000*256*2 bytes
    char* ws = (char*)d_ws;
    // slot A (ws+0, 51.2MB): xq [NN][128]fp8 -> t1q [NN][256]fp8 -> t2 [NN][48]fp16
    unsigned*  xq  = (unsigned*)ws;
    unsigned*  t1q = (unsigned*)ws;
    _Float16*  t2  = (_Float16*)ws;
    _Float16*  a0  = (_Float16*)(ws + 25600000);      // [NN][128] fp16 (25.6MB)
    _Float16*  S2  = (_Float16*)(ws + S);             // h0 / h1 slot (51.2MB)
    char* base2 = ws + 2 * S;
    int*   csr  = (int*)  (base2);                    // 12.8MB
    int*   offs = (int*)  (base2 + 12800000);
    float* dinv = (float*)(base2 + 13200064);
    float* ssb  = (float*)(base2 + 13602112);
    int*   bsum = (int*)  (base2 + 13604160);
    _Float16* wt0 = (_Float16*)(base2 + 13608320);    // [256][128]
    _Float16* wt1 = (_Float16*)(base2 + 13673856);    // [256][256]
    _Float16* wt2 = (_Float16*)(base2 + 13804928);    // [64][256]
    int*   hist = (int*)  (base2 + 13837696);         // NBKT*G+1 ints
    int*   epk  = (int*)  (base2 + 14640576);         // NE ints = 12.8MB
    float* part = (float*)(base2 + 27440576);         // 1024*512 floats = 2MB

    // CSR build: bucketed counting sort
    const int N2 = NBKT * G;
    const int NB2 = (N2 + 255) / 256;
    hist_kernel<<<G, 256, 0, stream>>>(dst, hist);
    scan1_kernel<<<NB2, 256, 0, stream>>>(hist, hist, bsum, N2);
    scan2_kernel<<<1, 1024, 0, stream>>>(bsum, NB2);
    scan3_kernel<<<NB2, 256, 0, stream>>>(hist, bsum, NB2, N2);
    scatter_kernel<<<G, 256, 0, stream>>>(src, dst, hist, epk);
    bucket_fill_kernel<<<NBKT, 256, 0, stream>>>(hist, epk, csr, offs, dinv);

    // weights -> fp16 transposed
    wtrans_kernel<FIN><<<(256 * FIN + 255) / 256, 256, 0, stream>>>(W0, wt0, HD, HD);
    wtrans_kernel<HD><<<(256 * HD + 255) / 256, 256, 0, stream>>>(W1, wt1, HD, HD);
    wtrans_kernel<HD><<<(64 * HD + 255) / 256, 256, 0, stream>>>(W2, wt2, CO, 64);

    const int MB = (NN + 127) / 128;   // 782

    // Layer 0 (reassociated): a0 = D^-1/2 (A+I) D^-1/2 x (fp8 gather); h0 = a0 @ W0
    conv_x_kernel<<<(NN * FIN / 4 + 255) / 256, 256, 0, stream>>>(x, dinv, xq);
    agg128_kernel<<<NN / 4, 256, 0, stream>>>((const unsigned short*)xq, offs, csr, dinv, a0);
    mfma_gemm_big<FIN, false, false, false><<<dim3(MB, 2), 256, 0, stream>>>(
        a0, FIN, wt0, nullptr, dinv, S2, HD);                   // h0 -> S2 (fp16)

    bn_part_kernel<<<1024, 256, 0, stream>>>(S2, part);
    bn_reduce_kernel<<<8, 256, 0, stream>>>(part, g0, be0, ssb);

    // Layer 1: t1 = dinv * (relu(bn(h0)) @ W1) -> fp8; h1 = dinv*(A+I)t1 -> fp16
    mfma_gemm_big<HD, true, true, true><<<dim3(MB, 2), 256, 0, stream>>>(
        S2, HD, wt1, ssb, dinv, t1q, HD);                       // t1q (fp8) -> slot A
    agg256_kernel<<<NN / 4, 256, 0, stream>>>(t1q, offs, csr, dinv, S2);  // h1 -> S2

    bn_part_kernel<<<1024, 256, 0, stream>>>(S2, part);
    bn_reduce_kernel<<<8, 256, 0, stream>>>(part, g1, be1, ssb);

    // Layer 2: t2 = dinv * (relu(bn(h1)) @ W2), 48-stride rows; agg + log_softmax
    mfma_gemm_kernel<HD, true, true><<<dim3(MB, 1), 256, 0, stream>>>(
        S2, HD, wt2, ssb, dinv, t2, COP, CO);                   // t2 -> slot A
    agg47_lsm_kernel<<<NN / 4, 256, 0, stream>>>(t2, offs, csr, dinv, b2, out);
}

// Round 10
// 591.621 us; speedup vs baseline: 1.2168x; 1.1615x over previous
//
#include <hip/hip_runtime.h>
#include <hip/hip_fp8.h>
#include <math.h>

#define NN 100000
#define NE 3200000
#define FIN 128
#define HD 256
#define CO 47
#define COP 48     // t2 row stride (fp16) for layer-2 gather
#define NBKT 196   // buckets of 512 nodes: dst>>9
#define G 1024     // partition blocks
#define CHUNK 3125 // NE / G exactly

typedef _Float16 h2 __attribute__((ext_vector_type(2)));
typedef _Float16 h4 __attribute__((ext_vector_type(4)));
typedef _Float16 h8 __attribute__((ext_vector_type(8)));
typedef float f32x2 __attribute__((ext_vector_type(2)));
typedef float f32x4 __attribute__((ext_vector_type(4)));

// ---------------- CSR build via bucketed counting sort ----------------

__global__ __launch_bounds__(256) void hist_kernel(const int* __restrict__ dst,
                                                   int* __restrict__ hist) {
    __shared__ int h[NBKT];
    int tid = threadIdx.x;
    for (int i = tid; i < NBKT; i += 256) h[i] = 0;
    __syncthreads();
    int base = blockIdx.x * CHUNK;
    for (int i = tid; i < CHUNK; i += 256)
        atomicAdd(&h[dst[base + i] >> 9], 1);
    __syncthreads();
    for (int i = tid; i < NBKT; i += 256) hist[i * G + blockIdx.x] = h[i];
}

__global__ void scan1_kernel(const int* __restrict__ in, int* __restrict__ out,
                             int* __restrict__ bsum, int n) {
    __shared__ int tmp[256];
    int t = threadIdx.x;
    int i = blockIdx.x * 256 + t;
    int v = (i < n) ? in[i] : 0;
    tmp[t] = v;
    __syncthreads();
    #pragma unroll
    for (int off = 1; off < 256; off <<= 1) {
        int u = (t >= off) ? tmp[t - off] : 0;
        __syncthreads();
        tmp[t] += u;
        __syncthreads();
    }
    if (i < n) out[i] = tmp[t] - v;
    if (t == 255) bsum[blockIdx.x] = tmp[255];
}

__global__ void scan2_kernel(int* __restrict__ bsum, int nb) {
    __shared__ int tmp[1024];
    int t = threadIdx.x;
    int v = (t < nb) ? bsum[t] : 0;
    tmp[t] = v;
    __syncthreads();
    #pragma unroll
    for (int off = 1; off < 1024; off <<= 1) {
        int u = (t >= off) ? tmp[t - off] : 0;
        __syncthreads();
        tmp[t] += u;
        __syncthreads();
    }
    if (t < nb) bsum[t] = tmp[t] - v;
    if (t == nb - 1) bsum[nb] = tmp[t];
}

__global__ void scan3_kernel(int* __restrict__ out, const int* __restrict__ bsum,
                             int nb, int n) {
    int i = blockIdx.x * 256 + threadIdx.x;
    if (i < n) out[i] += bsum[i >> 8];
    if (i == 0) out[n] = bsum[nb];
}

__global__ __launch_bounds__(256) void scatter_kernel(const int* __restrict__ src,
                                                      const int* __restrict__ dst,
                                                      const int* __restrict__ hscan,
                                                      int* __restrict__ epk) {
    __shared__ int cur[NBKT];
    int tid = threadIdx.x;
    for (int i = tid; i < NBKT; i += 256) cur[i] = hscan[i * G + blockIdx.x];
    __syncthreads();
    int base = blockIdx.x * CHUNK;
    for (int i = tid; i < CHUNK; i += 256) {
        int e = base + i;
        int d = dst[e];
        int slot = atomicAdd(&cur[d >> 9], 1);
        epk[slot] = ((d & 511) << 17) | src[e];
    }
}

__global__ __launch_bounds__(256) void bucket_fill_kernel(
    const int* __restrict__ hscan, const int* __restrict__ epk,
    int* __restrict__ csr, int* __restrict__ offs, float* __restrict__ dinv)
{
    __shared__ int deg[512], cur[512], a0[512], a1[512];
    int tid = threadIdx.x, b = blockIdx.x;
    int ebeg = hscan[b * G], eend = hscan[(b + 1) * G];
    deg[tid] = 0; deg[tid + 256] = 0;
    __syncthreads();
    for (int e = ebeg + tid; e < eend; e += 256)
        atomicAdd(&deg[((unsigned)epk[e]) >> 17], 1);
    __syncthreads();
    a0[tid] = deg[tid]; a0[tid + 256] = deg[tid + 256];
    __syncthreads();
    int* pin = a0; int* pout = a1;
    for (int off = 1; off < 512; off <<= 1) {
        #pragma unroll
        for (int q = 0; q < 2; ++q) {
            int p = tid + q * 256;
            pout[p] = pin[p] + ((p >= off) ? pin[p - off] : 0);
        }
        __syncthreads();
        int* t = pin; pin = pout; pout = t;
    }
    #pragma unroll
    for (int q = 0; q < 2; ++q) {
        int i = tid + q * 256;
        int excl = pin[i] - deg[i];
        cur[i] = excl;
        int node = b * 512 + i;
        if (node < NN) {
            offs[node] = ebeg + excl;
            dinv[node] = rsqrtf((float)deg[i] + 1.0f);
        }
    }
    if (b == 0 && tid == 0) offs[NN] = NE;
    __syncthreads();
    for (int e = ebeg + tid; e < eend; e += 256) {
        int pk = epk[e];
        int p = atomicAdd(&cur[((unsigned)pk) >> 17], 1);
        csr[ebeg + p] = pk & 0x1FFFF;
    }
}

// ---------------- weight convert ----------------

template<int K>
__global__ void wtrans_kernel(const float* __restrict__ W, _Float16* __restrict__ Wt,
                              int N, int NP) {
    int i = blockIdx.x * 256 + threadIdx.x;
    if (i >= NP * K) return;
    int n = i / K, k = i % K;
    float v = (n < N) ? W[(size_t)k * N + n] : 0.0f;
    Wt[i] = (_Float16)v;
}

// ---------------- x -> fp8 e4m3 (OCP) via HW cvt, pre-scaled by dinv ----------------

__global__ void conv_x_kernel(const float* __restrict__ x, const float* __restrict__ dinv,
                              unsigned* __restrict__ xq) {
    int i = blockIdx.x * 256 + threadIdx.x;     // over NN*FIN/4
    if (i >= NN * FIN / 4) return;
    int r = i >> 5;
    float4 v = ((const float4*)x)[i];
    float dv = dinv[r];
    int u = __builtin_amdgcn_cvt_pk_fp8_f32(v.x * dv, v.y * dv, 0, false);
    u = __builtin_amdgcn_cvt_pk_fp8_f32(v.z * dv, v.w * dv, u, true);
    xq[i] = (unsigned)u;
}

// ---------------- aggregation (wave per node, atomic-free, HW fp8 decode) --------

__global__ __launch_bounds__(256) void agg128_kernel(
    const unsigned short* __restrict__ xq, const int* __restrict__ offs,
    const int* __restrict__ csr, const float* __restrict__ dinv,
    _Float16* __restrict__ out)
{
    int lane = threadIdx.x & 63;
    int v = blockIdx.x * 4 + (threadIdx.x >> 6);
    unsigned sv = xq[(size_t)v * 64 + lane];    // 2 fp8 per lane
    f32x2 acc = __builtin_amdgcn_cvt_pk_f32_fp8((int)sv, false);
    int b = offs[v], e = offs[v + 1], j = b;
    int s[8];
    if (j + 8 <= e) {
        #pragma unroll
        for (int q = 0; q < 8; ++q) s[q] = csr[j + q];
    }
    for (; j + 8 <= e; ) {
        int nj = j + 8;
        int ns[8];
        if (nj + 8 <= e) {
            #pragma unroll
            for (int q = 0; q < 8; ++q) ns[q] = csr[nj + q];
        }
        #pragma unroll
        for (int q = 0; q < 8; ++q) {
            unsigned t = xq[(size_t)s[q] * 64 + lane];
            acc += __builtin_amdgcn_cvt_pk_f32_fp8((int)t, false);
        }
        #pragma unroll
        for (int q = 0; q < 8; ++q) s[q] = ns[q];
        j = nj;
    }
    for (; j < e; ++j) {
        unsigned t = xq[(size_t)csr[j] * 64 + lane];
        acc += __builtin_amdgcn_cvt_pk_f32_fp8((int)t, false);
    }
    float dv = dinv[v];
    h2 o; o[0] = (_Float16)(acc[0] * dv); o[1] = (_Float16)(acc[1] * dv);
    ((h2*)out)[(size_t)v * 64 + lane] = o;
}

// t1 is fp8: 256 B rows, u32/lane; HW decode; fp32 accumulate; fp16 out (h1)
__global__ __launch_bounds__(256) void agg256_kernel(
    const unsigned* __restrict__ t1q, const int* __restrict__ offs,
    const int* __restrict__ csr, const float* __restrict__ dinv,
    _Float16* __restrict__ out)
{
    int lane = threadIdx.x & 63;
    int v = blockIdx.x * 4 + (threadIdx.x >> 6);
    unsigned sv = t1q[(size_t)v * 64 + lane];   // 4 fp8 per lane
    f32x2 acc01 = __builtin_amdgcn_cvt_pk_f32_fp8((int)sv, false);
    f32x2 acc23 = __builtin_amdgcn_cvt_pk_f32_fp8((int)sv, true);
    int b = offs[v], e = offs[v + 1], j = b;
    int s[8];
    if (j + 8 <= e) {
        #pragma unroll
        for (int q = 0; q < 8; ++q) s[q] = csr[j + q];
    }
    for (; j + 8 <= e; ) {
        int nj = j + 8;
        int ns[8];
        if (nj + 8 <= e) {
            #pragma unroll
            for (int q = 0; q < 8; ++q) ns[q] = csr[nj + q];
        }
        #pragma unroll
        for (int q = 0; q < 8; ++q) {
            unsigned t = t1q[(size_t)s[q] * 64 + lane];
            acc01 += __builtin_amdgcn_cvt_pk_f32_fp8((int)t, false);
            acc23 += __builtin_amdgcn_cvt_pk_f32_fp8((int)t, true);
        }
        #pragma unroll
        for (int q = 0; q < 8; ++q) s[q] = ns[q];
        j = nj;
    }
    for (; j < e; ++j) {
        unsigned t = t1q[(size_t)csr[j] * 64 + lane];
        acc01 += __builtin_amdgcn_cvt_pk_f32_fp8((int)t, false);
        acc23 += __builtin_amdgcn_cvt_pk_f32_fp8((int)t, true);
    }
    float dv = dinv[v];
    h4 o; o[0] = (_Float16)(acc01[0] * dv); o[1] = (_Float16)(acc01[1] * dv);
    o[2] = (_Float16)(acc23[0] * dv); o[3] = (_Float16)(acc23[1] * dv);
    ((h4*)out)[(size_t)v * 64 + lane] = o;
}

__global__ __launch_bounds__(256) void agg47_lsm_kernel(
    const _Float16* __restrict__ t2, const int* __restrict__ offs,
    const int* __restrict__ csr, const float* __restrict__ dinv,
    const float* __restrict__ bias, float* __restrict__ out)
{
    int lane = threadIdx.x & 63;
    int v = blockIdx.x * 4 + (threadIdx.x >> 6);
    bool act = lane < CO;
    float acc = act ? (float)t2[(size_t)v * COP + lane] : 0.0f;
    int b = offs[v], e = offs[v + 1], j = b;
    int s[8];
    if (j + 8 <= e) {
        #pragma unroll
        for (int q = 0; q < 8; ++q) s[q] = csr[j + q];
    }
    for (; j + 8 <= e; ) {
        int nj = j + 8;
        int ns[8];
        if (nj + 8 <= e) {
            #pragma unroll
            for (int q = 0; q < 8; ++q) ns[q] = csr[nj + q];
        }
        if (act) {
            #pragma unroll
            for (int q = 0; q < 8; ++q) acc += (float)t2[(size_t)s[q] * COP + lane];
        }
        #pragma unroll
        for (int q = 0; q < 8; ++q) s[q] = ns[q];
        j = nj;
    }
    for (; j < e; ++j) if (act) acc += (float)t2[(size_t)csr[j] * COP + lane];
    float val = act ? fmaf(acc, dinv[v], bias[lane]) : -1e30f;
    float m = val;
    #pragma unroll
    for (int o = 32; o > 0; o >>= 1) m = fmaxf(m, __shfl_xor(m, o, 64));
    float ex = act ? expf(val - m) : 0.0f;
    float sum = ex;
    #pragma unroll
    for (int o = 32; o > 0; o >>= 1) sum += __shfl_xor(sum, o, 64);
    if (act) out[(size_t)v * CO + lane] = val - m - logf(sum);
}

// ---------------- big MFMA GEMM: BM=128, BN=128, BK=64, 4 waves (2x2), 64x64/wave ----

#define LDS_PAD 8

template<int K, bool XFORM, bool EPI_DINV, bool OUT8>
__global__ __launch_bounds__(256) void mfma_gemm_big(
    const _Float16* __restrict__ A, int lda,
    const _Float16* __restrict__ Wt,
    const float* __restrict__ ss, const float* __restrict__ dinv,
    void* __restrict__ outp, int ldo)
{
    __shared__ __align__(16) _Float16 As[128][64 + LDS_PAD];
    __shared__ __align__(16) _Float16 Bs[128][64 + LDS_PAD];
    __shared__ float SS[2 * K];
    const int row0 = blockIdx.x * 128;
    const int col0 = blockIdx.y * 128;
    const int tid = threadIdx.x;
    if (XFORM) {
        for (int i = tid; i < 2 * K; i += 256) SS[i] = ss[i];
    }
    const int lane = tid & 63;
    const int wv = tid >> 6;
    const int wr = wv >> 1, wc = wv & 1;
    const int fr = lane & 15;
    const int kb = (lane >> 4) * 8;

    f32x4 acc[4][4];
    #pragma unroll
    for (int m = 0; m < 4; ++m)
        #pragma unroll
        for (int n = 0; n < 4; ++n)
            acc[m][n] = (f32x4){0.f, 0.f, 0.f, 0.f};

    if (XFORM) __syncthreads();

    for (int k0 = 0; k0 < K; k0 += 64) {
        #pragma unroll
        for (int p = 0; p < 4; ++p) {
            int c = p * 256 + tid;
            int m = c >> 3, kk = (c & 7) * 8;
            int r = row0 + m;
            h8 av = {};
            if (r < NN) av = *(const h8*)&A[(size_t)r * lda + k0 + kk];
            if (XFORM) {
                #pragma unroll
                for (int j = 0; j < 8; ++j) {
                    float a = (float)av[j];
                    a = fmaxf(fmaf(a, SS[k0 + kk + j], SS[K + k0 + kk + j]), 0.0f);
                    av[j] = (_Float16)a;
                }
            }
            *(h8*)&As[m][kk] = av;
        }
        #pragma unroll
        for (int p = 0; p < 4; ++p) {
            int c = p * 256 + tid;
            int n = c >> 3, kk = (c & 7) * 8;
            h8 bv = *(const h8*)&Wt[(size_t)(col0 + n) * K + k0 + kk];
            *(h8*)&Bs[n][kk] = bv;
        }
        __syncthreads();
        #pragma unroll
        for (int ks = 0; ks < 2; ++ks) {
            h8 a[4], b[4];
            #pragma unroll
            for (int m = 0; m < 4; ++m)
                a[m] = *(const h8*)&As[wr * 64 + m * 16 + fr][ks * 32 + kb];
            #pragma unroll
            for (int n = 0; n < 4; ++n)
                b[n] = *(const h8*)&Bs[wc * 64 + n * 16 + fr][ks * 32 + kb];
            #pragma unroll
            for (int m = 0; m < 4; ++m)
                #pragma unroll
                for (int n = 0; n < 4; ++n)
                    acc[m][n] = __builtin_amdgcn_mfma_f32_16x16x32_f16(a[m], b[n], acc[m][n], 0, 0, 0);
        }
        __syncthreads();
    }

    const int fq = lane >> 4;
    #pragma unroll
    for (int m = 0; m < 4; ++m) {
        #pragma unroll
        for (int j = 0; j < 4; ++j) {
            int r = row0 + wr * 64 + m * 16 + fq * 4 + j;
            if (r >= NN) continue;
            float dv = EPI_DINV ? dinv[r] : 1.0f;
            #pragma unroll
            for (int n = 0; n < 4; n += 2) {
                int c0 = col0 + wc * 64 + n * 16 + fr;
                int c1 = c0 + 16;
                float v0 = acc[m][n][j] * dv;
                float v1 = acc[m][n + 1][j] * dv;
                if (OUT8) {
                    int pk = __builtin_amdgcn_cvt_pk_fp8_f32(v0, v1, 0, false);
                    ((unsigned char*)outp)[(size_t)r * ldo + c0] = (unsigned char)(pk & 0xFF);
                    ((unsigned char*)outp)[(size_t)r * ldo + c1] = (unsigned char)((pk >> 8) & 0xFF);
                } else {
                    ((_Float16*)outp)[(size_t)r * ldo + c0] = (_Float16)v0;
                    ((_Float16*)outp)[(size_t)r * ldo + c1] = (_Float16)v1;
                }
            }
        }
    }
}

// ---------------- narrow MFMA GEMM for layer 2 (BN=64 cols) ----------------

template<int K, bool XFORM, bool EPI_DINV>
__global__ __launch_bounds__(256) void mfma_gemm_kernel(
    const _Float16* __restrict__ A, int lda,
    const _Float16* __restrict__ Wt,
    const float* __restrict__ ss, const float* __restrict__ dinv,
    _Float16* __restrict__ out, int ldo, int ncolsO)
{
    __shared__ __align__(16) _Float16 As[128][32 + LDS_PAD];
    __shared__ __align__(16) _Float16 Bs[64][32 + LDS_PAD];
    __shared__ float SS[2 * K];
    const int row0 = blockIdx.x * 128;
    const int col0 = blockIdx.y * 64;
    const int tid = threadIdx.x;
    if (XFORM) {
        for (int i = tid; i < 2 * K; i += 256) SS[i] = ss[i];
    }
    const int lane = tid & 63;
    const int wv = tid >> 6;
    const int wr = wv >> 1, wc = wv & 1;
    const int fr = lane & 15;
    const int kb = (lane >> 4) * 8;

    f32x4 acc[4][2];
    #pragma unroll
    for (int m = 0; m < 4; ++m)
        #pragma unroll
        for (int n = 0; n < 2; ++n)
            acc[m][n] = (f32x4){0.f, 0.f, 0.f, 0.f};

    if (XFORM) __syncthreads();

    for (int k0 = 0; k0 < K; k0 += 32) {
        #pragma unroll
        for (int p = 0; p < 2; ++p) {
            int idx = (p * 256 + tid) * 8;
            int m = idx >> 5, kk = idx & 31;
            int r = row0 + m;
            h8 av = {};
            if (r < NN) av = *(const h8*)&A[(size_t)r * lda + k0 + kk];
            if (XFORM) {
                #pragma unroll
                for (int j = 0; j < 8; ++j) {
                    float a = (float)av[j];
                    a = fmaxf(fmaf(a, SS[k0 + kk + j], SS[K + k0 + kk + j]), 0.0f);
                    av[j] = (_Float16)a;
                }
            }
            *(h8*)&As[m][kk] = av;
        }
        {
            int idx = tid * 8;
            int n = idx >> 5, kk = idx & 31;
            h8 bv = *(const h8*)&Wt[(size_t)(col0 + n) * K + k0 + kk];
            *(h8*)&Bs[n][kk] = bv;
        }
        __syncthreads();
        h8 a[4], b[2];
        #pragma unroll
        for (int m = 0; m < 4; ++m)
            a[m] = *(const h8*)&As[wr * 64 + m * 16 + fr][kb];
        #pragma unroll
        for (int n = 0; n < 2; ++n)
            b[n] = *(const h8*)&Bs[wc * 32 + n * 16 + fr][kb];
        #pragma unroll
        for (int m = 0; m < 4; ++m)
            #pragma unroll
            for (int n = 0; n < 2; ++n)
                acc[m][n] = __builtin_amdgcn_mfma_f32_16x16x32_f16(a[m], b[n], acc[m][n], 0, 0, 0);
        __syncthreads();
    }

    const int fq = lane >> 4;
    #pragma unroll
    for (int m = 0; m < 4; ++m) {
        #pragma unroll
        for (int j = 0; j < 4; ++j) {
            int r = row0 + wr * 64 + m * 16 + fq * 4 + j;
            if (r >= NN) continue;
            float dv = EPI_DINV ? dinv[r] : 1.0f;
            #pragma unroll
            for (int n = 0; n < 2; ++n) {
                int c = col0 + wc * 32 + n * 16 + fr;
                if (c < ncolsO) out[(size_t)r * ldo + c] = (_Float16)(acc[m][n][j] * dv);
            }
        }
    }
}

// ---------------- BatchNorm stats: vectorized partials + fused reduce/finalize ----

__global__ __launch_bounds__(256) void bn_part_kernel(const _Float16* __restrict__ h,
                                                      float* __restrict__ part) {
    int tid = threadIdx.x;
    int fg = tid & 63;
    int rg = tid >> 6;
    float s1[4] = {}, s2[4] = {};
    for (int r = blockIdx.x * 4 + rg; r < NN; r += 4096) {
        h4 v = ((const h4*)(h + (size_t)r * HD))[fg];
        #pragma unroll
        for (int j = 0; j < 4; ++j) {
            float f = (float)v[j];
            s1[j] += f; s2[j] += f * f;
        }
    }
    __shared__ float sm[256][8];
    #pragma unroll
    for (int j = 0; j < 4; ++j) { sm[tid][j] = s1[j]; sm[tid][4 + j] = s2[j]; }
    __syncthreads();
    if (tid < 64) {
        float o1[4] = {}, o2[4] = {};
        #pragma unroll
        for (int r = 0; r < 4; ++r)
            #pragma unroll
            for (int j = 0; j < 4; ++j) {
                o1[j] += sm[r * 64 + tid][j];
                o2[j] += sm[r * 64 + tid][4 + j];
            }
        #pragma unroll
        for (int j = 0; j < 4; ++j) {
            part[(size_t)blockIdx.x * 512 + tid * 4 + j] = o1[j];
            part[(size_t)blockIdx.x * 512 + 256 + tid * 4 + j] = o2[j];
        }
    }
}

__global__ __launch_bounds__(256) void bn_reduce_kernel(const float* __restrict__ part,
                                                        const float* __restrict__ g,
                                                        const float* __restrict__ be,
                                                        float* __restrict__ ss) {
    int f = blockIdx.x * 32 + (threadIdx.x & 31);
    int c = threadIdx.x >> 5;
    float s1 = 0.f, s2 = 0.f;
    for (int b = c; b < 1024; b += 8) {
        s1 += part[(size_t)b * 512 + f];
        s2 += part[(size_t)b * 512 + 256 + f];
    }
    __shared__ float m1[8][32], m2[8][32];
    m1[c][threadIdx.x & 31] = s1; m2[c][threadIdx.x & 31] = s2;
    __syncthreads();
    if (threadIdx.x < 32) {
        float t1 = 0.f, t2 = 0.f;
        #pragma unroll
        for (int q = 0; q < 8; ++q) { t1 += m1[q][threadIdx.x]; t2 += m2[q][threadIdx.x]; }
        float mean = t1 * (1.0f / NN);
        float var = t2 * (1.0f / NN) - mean * mean;
        float sc = g[f] * rsqrtf(var + 1e-5f);
        ss[f] = sc;
        ss[HD + f] = be[f] - mean * sc;
    }
}

// ---------------- launch ----------------

extern "C" void kernel_launch(void* const* d_in, const int* in_sizes, int n_in,
                              void* d_out, int out_size, void* d_ws, size_t ws_size,
                              hipStream_t stream) {
    const float* x   = (const float*)d_in[0];
    const int*   ei  = (const int*)d_in[1];
    const float* W0  = (const float*)d_in[3];
    const float* g0  = (const float*)d_in[5];
    const float* be0 = (const float*)d_in[6];
    const float* W1  = (const float*)d_in[7];
    const float* g1  = (const float*)d_in[9];
    const float* be1 = (const float*)d_in[10];
    const float* W2  = (const float*)d_in[11];
    const float* b2  = (const float*)d_in[12];
    float* out = (float*)d_out;

    const int* src = ei;            // edge_index[0]
    const int* dst = ei + NE;       // edge_index[1]

    const size_t S = 51200000;                        // 100000*256*2 bytes
    char* ws = (char*)d_ws;
    // slot A (ws+0, 51.2MB): xq [NN][128]fp8 -> t1q [NN][256]fp8 -> t2 [NN][48]fp16
    unsigned*  xq  = (unsigned*)ws;
    unsigned*  t1q = (unsigned*)ws;
    _Float16*  t2  = (_Float16*)ws;
    _Float16*  a0  = (_Float16*)(ws + 25600000);      // [NN][128] fp16 (25.6MB)
    _Float16*  S2  = (_Float16*)(ws + S);             // h0 / h1 slot (51.2MB)
    char* base2 = ws + 2 * S;
    int*   csr  = (int*)  (base2);                    // 12.8MB
    int*   offs = (int*)  (base2 + 12800000);
    float* dinv = (float*)(base2 + 13200064);
    float* ssb  = (float*)(base2 + 13602112);
    int*   bsum = (int*)  (base2 + 13604160);
    _Float16* wt0 = (_Float16*)(base2 + 13608320);    // [256][128]
    _Float16* wt1 = (_Float16*)(base2 + 13673856);    // [256][256]
    _Float16* wt2 = (_Float16*)(base2 + 13804928);    // [64][256]
    int*   hist = (int*)  (base2 + 13837696);         // NBKT*G+1 ints
    int*   epk  = (int*)  (base2 + 14640576);         // NE ints = 12.8MB
    float* part = (float*)(base2 + 27440576);         // 1024*512 floats = 2MB

    // CSR build: bucketed counting sort
    const int N2 = NBKT * G;
    const int NB2 = (N2 + 255) / 256;
    hist_kernel<<<G, 256, 0, stream>>>(dst, hist);
    scan1_kernel<<<NB2, 256, 0, stream>>>(hist, hist, bsum, N2);
    scan2_kernel<<<1, 1024, 0, stream>>>(bsum, NB2);
    scan3_kernel<<<NB2, 256, 0, stream>>>(hist, bsum, NB2, N2);
    scatter_kernel<<<G, 256, 0, stream>>>(src, dst, hist, epk);
    bucket_fill_kernel<<<NBKT, 256, 0, stream>>>(hist, epk, csr, offs, dinv);

    // weights -> fp16 transposed
    wtrans_kernel<FIN><<<(256 * FIN + 255) / 256, 256, 0, stream>>>(W0, wt0, HD, HD);
    wtrans_kernel<HD><<<(256 * HD + 255) / 256, 256, 0, stream>>>(W1, wt1, HD, HD);
    wtrans_kernel<HD><<<(64 * HD + 255) / 256, 256, 0, stream>>>(W2, wt2, CO, 64);

    const int MB = (NN + 127) / 128;   // 782

    // Layer 0 (reassociated): a0 = D^-1/2 (A+I) D^-1/2 x (fp8 gather); h0 = a0 @ W0
    conv_x_kernel<<<(NN * FIN / 4 + 255) / 256, 256, 0, stream>>>(x, dinv, xq);
    agg128_kernel<<<NN / 4, 256, 0, stream>>>((const unsigned short*)xq, offs, csr, dinv, a0);
    mfma_gemm_big<FIN, false, false, false><<<dim3(MB, 2), 256, 0, stream>>>(
        a0, FIN, wt0, nullptr, dinv, S2, HD);                   // h0 -> S2 (fp16)

    bn_part_kernel<<<1024, 256, 0, stream>>>(S2, part);
    bn_reduce_kernel<<<8, 256, 0, stream>>>(part, g0, be0, ssb);

    // Layer 1: t1 = dinv * (relu(bn(h0)) @ W1) -> fp8; h1 = dinv*(A+I)t1 -> fp16
    mfma_gemm_big<HD, true, true, true><<<dim3(MB, 2), 256, 0, stream>>>(
        S2, HD, wt1, ssb, dinv, t1q, HD);                       // t1q (fp8) -> slot A
    agg256_kernel<<<NN / 4, 256, 0, stream>>>(t1q, offs, csr, dinv, S2);  // h1 -> S2

    bn_part_kernel<<<1024, 256, 0, stream>>>(S2, part);
    bn_reduce_kernel<<<8, 256, 0, stream>>>(part, g1, be1, ssb);

    // Layer 2: t2 = dinv * (relu(bn(h1)) @ W2), 48-stride rows; agg + log_softmax
    mfma_gemm_kernel<HD, true, true><<<dim3(MB, 1), 256, 0, stream>>>(
        S2, HD, wt2, ssb, dinv, t2, COP, CO);                   // t2 -> slot A
    agg47_lsm_kernel<<<NN / 4, 256, 0, stream>>>(t2, offs, csr, dinv, b2, out);
}